// Round 9
// baseline (117.004 us; speedup 1.0000x reference)
//
#include <hip/hip_runtime.h>

#define B_ 32
#define T_ 64
#define I_ 256
#define H_ 512

static constexpr float ALPHA_F = 0.951229424500714f;   // exp(-1/20)
static constexpr float OMD_F   = 0.048770575499286f;   // 1 - decay
static constexpr float ETA_F   = 0.1f;
static constexpr float CSCALE  = 0.02f;                // 0.2 * ETA

// ---------------- fast tanh: exact at saturation, ~1e-6 rel elsewhere ----------------
__device__ __forceinline__ float tanh_fast(float x) {
  float xc = fminf(fmaxf(x, -15.f), 15.f);
  float e = __expf(2.f * xc);
  return (e - 1.f) * __builtin_amdgcn_rcpf(e + 1.f);
}

// ---------------- DPP full-wave (64-lane) sum; valid result in lane 63 ----------------
template <int CTRL>
__device__ __forceinline__ float dpp_add(float x) {
  int mv = __builtin_amdgcn_update_dpp(0, __float_as_int(x), CTRL, 0xF, 0xF, true);
  return x + __int_as_float(mv);
}
__device__ __forceinline__ float wave_sum_dpp(float x) {
  x = dpp_add<0x111>(x);  // row_shr:1
  x = dpp_add<0x112>(x);  // row_shr:2
  x = dpp_add<0x114>(x);  // row_shr:4
  x = dpp_add<0x118>(x);  // row_shr:8
  x = dpp_add<0x142>(x);  // row_bcast:15
  x = dpp_add<0x143>(x);  // row_bcast:31 -> lane63 = full 64-lane sum
  return x;
}

// ---------------- Kernel 1: projection GEMM (vector LDS reads, 4 kk/iter) ----------------
__global__ __launch_bounds__(256) void proj_gemm(const float* __restrict__ x,
                                                 const float* __restrict__ W,
                                                 float* __restrict__ P) {
  __shared__ float As[64][68];   // [m][kk], row 272B = 16B-aligned
  __shared__ float Bs[64][68];   // [n][kk]
  const int m0 = blockIdx.x * 64;
  const int n0 = blockIdx.y * 64;
  const int tid = threadIdx.x;
  const int ty = tid >> 4, tx = tid & 15;
  float acc[4][4] = {};
  for (int k0 = 0; k0 < I_; k0 += 64) {
#pragma unroll
    for (int e = 0; e < 16; ++e) {
      int idx = tid + e * 256;
      int r = idx >> 6, c = idx & 63;
      As[r][c] = x[(size_t)(m0 + r) * I_ + k0 + c];
      Bs[r][c] = W[(size_t)(n0 + r) * I_ + k0 + c];
    }
    __syncthreads();
#pragma unroll 4
    for (int kq = 0; kq < 16; ++kq) {
      float4 a[4], bb[4];
#pragma unroll
      for (int i = 0; i < 4; ++i) a[i]  = *reinterpret_cast<const float4*>(&As[ty * 4 + i][kq * 4]);
#pragma unroll
      for (int j = 0; j < 4; ++j) bb[j] = *reinterpret_cast<const float4*>(&Bs[tx * 4 + j][kq * 4]);
#pragma unroll
      for (int i = 0; i < 4; ++i)
#pragma unroll
        for (int j = 0; j < 4; ++j)
          acc[i][j] += a[i].x * bb[j].x + a[i].y * bb[j].y
                     + a[i].z * bb[j].z + a[i].w * bb[j].w;
    }
    __syncthreads();
  }
#pragma unroll
  for (int i = 0; i < 4; ++i) {
    float4 o = make_float4(acc[i][0], acc[i][1], acc[i][2], acc[i][3]);
    *reinterpret_cast<float4*>(&P[(size_t)(m0 + ty * 4 + i) * 1024 + n0 + tx * 4]) = o;
  }
}

// ---------------- Kernel 2: k-side scan — 1 wave/block, 256 blocks (full-chip) ----------------
__global__ __launch_bounds__(64) void kscan_kernel(const float* __restrict__ proj,
                                                   float* __restrict__ keys,
                                                   float* __restrict__ ktg) {
  const int gid = blockIdx.x * 64 + threadIdx.x;
  const int b = gid >> 9;
  const int h = gid & (H_ - 1);
  const float* pkk = proj + (size_t)b * T_ * 1024 + h;
  float* ko  = keys + ((size_t)b * T_) * H_ + h;
  float* kto = ktg  + ((size_t)b * T_) * H_ + h;
  float kvv = 0.f, kt = 0.f;
#pragma unroll 8
  for (int t = 0; t < T_; ++t) {
    float ik = pkk[(size_t)t * 1024];
    kvv = ALPHA_F * kvv + ik;
    float k = tanh_fast(kvv);
    kt = ALPHA_F * kt + OMD_F * k;
    ko[(size_t)t * H_]  = k;
    kto[(size_t)t * H_] = kt;
  }
}

// ---------------- Kernel 3: dots GEMM — C[b][t][s] = 0.02 * (k_t . kt_s) ----------------
__global__ __launch_bounds__(512) void dots_kernel(const float* __restrict__ keys,
                                                   const float* __restrict__ ktg,
                                                   float* __restrict__ C) {
  const int b = blockIdx.y;
  const int t = blockIdx.x * 8 + (threadIdx.x >> 6);
  const int lane = threadIdx.x & 63;
  const float* krow = keys + ((size_t)b * T_ + t) * H_ + 4 * lane;
  float4 k0 = *reinterpret_cast<const float4*>(krow);
  float4 k1 = *reinterpret_cast<const float4*>(krow + 256);
  const float* tb = ktg + (size_t)b * T_ * H_ + 4 * lane;
  float* Cb = C + ((size_t)b * T_ + t) * T_;
#pragma unroll 8
  for (int s = 0; s < T_; ++s) {
    const float* ar = tb + (size_t)s * H_;
    float4 a0 = *reinterpret_cast<const float4*>(ar);
    float4 a1 = *reinterpret_cast<const float4*>(ar + 256);
    float p = a0.x * k0.x + a0.y * k0.y + a0.z * k0.z + a0.w * k0.w
            + a1.x * k1.x + a1.y * k1.y + a1.z * k1.z + a1.w * k1.w;
    p = wave_sum_dpp(p);
    if (lane == 63) Cb[s] = CSCALE * p;
  }
}

// ---------------- Kernel 4: v-side scan — 1 wave/block, all state in registers ----------------
#define CASE4(Q) \
  case 4*Q+0: vqv[Q].x = vt; break; \
  case 4*Q+1: vqv[Q].y = vt; break; \
  case 4*Q+2: vqv[Q].z = vt; break; \
  case 4*Q+3: vqv[Q].w = vt; break;

#define VSTEP(T_IDX, CUR, NXT)                                                  \
  {                                                                             \
    const int tt = (T_IDX);                                                     \
    _Pragma("unroll")                                                           \
    for (int q = 0; q < 16; ++q)                                                \
      NXT[q] = *reinterpret_cast<const float4*>(&Cs[(tt + 1) & 63][4 * q]);     \
    float p0 = 0.f, p1 = 0.f, p2 = 0.f, p3 = 0.f;                               \
    _Pragma("unroll")                                                           \
    for (int q = 0; q < 16; ++q) {                                              \
      p0 += CUR[q].x * vqv[q].x;                                                \
      p1 += CUR[q].y * vqv[q].y;                                                \
      p2 += CUR[q].z * vqv[q].z;                                                \
      p3 += CUR[q].w * vqv[q].w;                                                \
    }                                                                           \
    float ikv = (p0 + p1) + (p2 + p3);                                          \
    float ivc = iv0; iv0 = iv1;                                                 \
    iv1 = (tt + 2 < T_) ? pv[(size_t)(tt + 2) * 1024] : 0.f;                    \
    vv = ALPHA_F * vv + ivc + ikv;                                              \
    float v = tanh_fast(vv);                                                    \
    vt = ALPHA_F * vt + OMD_F * v;                                              \
    switch (tt) {                                                               \
      CASE4(0)  CASE4(1)  CASE4(2)  CASE4(3)                                    \
      CASE4(4)  CASE4(5)  CASE4(6)  CASE4(7)                                    \
      CASE4(8)  CASE4(9)  CASE4(10) CASE4(11)                                   \
      CASE4(12) CASE4(13) CASE4(14) CASE4(15)                                   \
    }                                                                           \
    vo[(size_t)tt * H_]  = v;                                                   \
    vto[(size_t)tt * H_] = vt;                                                  \
  }

__global__ __launch_bounds__(64, 1) void vscan_kernel(const float* __restrict__ proj,
                                                      const float* __restrict__ C,
                                                      float* __restrict__ vals,
                                                      float* __restrict__ vtg) {
  __shared__ float Cs[T_][T_];   // 16 KB
  const int b    = blockIdx.x >> 3;
  const int lane = threadIdx.x;                 // 0..63
  const int h    = ((blockIdx.x & 7) << 6) + lane;

  const float* Cb = C + (size_t)b * T_ * T_;
#pragma unroll
  for (int e = 0; e < 16; ++e)
    reinterpret_cast<float4*>(&Cs[0][0])[lane + (e << 6)] =
        reinterpret_cast<const float4*>(Cb)[lane + (e << 6)];

  const float* pv = proj + (size_t)b * T_ * 1024 + 512 + h;
  float* vo  = vals + ((size_t)b * T_) * H_ + h;
  float* vto = vtg  + ((size_t)b * T_) * H_ + h;

  float vv = 0.f, vt = 0.f;
  float4 vqv[16];
#pragma unroll
  for (int q = 0; q < 16; ++q) vqv[q] = make_float4(0.f, 0.f, 0.f, 0.f);

  float iv0 = pv[0];
  float iv1 = pv[1024];

  __syncthreads();   // Cs ready

  float4 ca[16], cbuf[16];
#pragma unroll
  for (int q = 0; q < 16; ++q)
    ca[q] = *reinterpret_cast<const float4*>(&Cs[0][4 * q]);

  for (int t2 = 0; t2 < T_; t2 += 2) {
    VSTEP(t2,     ca,   cbuf)
    VSTEP(t2 + 1, cbuf, ca)
  }
}

// ---------------- Kernel 5: mem = ETA * vt^T @ kt (per batch, K=T=64, vector LDS reads) ----------------
__global__ __launch_bounds__(256) void mem_gemm(const float* __restrict__ vtg,
                                                const float* __restrict__ ktg,
                                                float* __restrict__ mem) {
  const int b = blockIdx.z;
  const int i0 = blockIdx.y * 64;
  const int j0 = blockIdx.x * 64;
  __shared__ float Vs[64][68];   // [t][i], 16B-aligned rows
  __shared__ float Ks[64][68];   // [t][j]
  const int tid = threadIdx.x;
  const int ty = tid >> 4, tx = tid & 15;
  const float* vb = vtg + (size_t)b * T_ * H_;
  const float* kb = ktg + (size_t)b * T_ * H_;
#pragma unroll
  for (int e = 0; e < 16; ++e) {
    int idx = tid + e * 256;
    int t = idx >> 6, c = idx & 63;
    Vs[t][c] = vb[(size_t)t * H_ + i0 + c];
    Ks[t][c] = kb[(size_t)t * H_ + j0 + c];
  }
  __syncthreads();
  float acc[4][4] = {};
#pragma unroll 8
  for (int t = 0; t < 64; ++t) {
    float4 a  = *reinterpret_cast<const float4*>(&Vs[t][ty * 4]);
    float4 bb = *reinterpret_cast<const float4*>(&Ks[t][tx * 4]);
    float av[4] = {a.x, a.y, a.z, a.w};
    float bv[4] = {bb.x, bb.y, bb.z, bb.w};
#pragma unroll
    for (int i = 0; i < 4; ++i)
#pragma unroll
      for (int j = 0; j < 4; ++j) acc[i][j] += av[i] * bv[j];
  }
  float* mb = mem + (size_t)b * H_ * H_;
#pragma unroll
  for (int i = 0; i < 4; ++i) {
    float4 o = make_float4(ETA_F * acc[i][0], ETA_F * acc[i][1],
                           ETA_F * acc[i][2], ETA_F * acc[i][3]);
    *reinterpret_cast<float4*>(&mb[(size_t)(i0 + ty * 4 + i) * H_ + j0 + tx * 4]) = o;
  }
}

extern "C" void kernel_launch(void* const* d_in, const int* in_sizes, int n_in,
                              void* d_out, int out_size, void* d_ws, size_t ws_size,
                              hipStream_t stream) {
  const float* x = (const float*)d_in[0];   // (B,T,I)
  const float* W = (const float*)d_in[1];   // (2H,I)
  float* out = (float*)d_out;
  float* mem  = out;                             // B*H*H
  float* keys = out + (size_t)B_ * H_ * H_;      // B*T*H
  float* vals = keys + (size_t)B_ * T_ * H_;

  // Scratch parked in the mem region (overwritten last by mem_gemm):
  //   proj: [0, 8MB) ; C: [16MB, 16.5MB)
  float* proj = mem;
  float* Cbuf = mem + (size_t)4 * 1024 * 1024;
  float* ktg = (float*)d_ws;
  float* vtg = ktg + (size_t)B_ * T_ * H_;

  proj_gemm<<<dim3(32, 16), 256, 0, stream>>>(x, W, proj);
  kscan_kernel<<<dim3(B_ * H_ / 64), 64, 0, stream>>>(proj, keys, ktg);
  dots_kernel<<<dim3(8, B_), 512, 0, stream>>>(keys, ktg, Cbuf);
  vscan_kernel<<<dim3(8 * B_), 64, 0, stream>>>(proj, Cbuf, vals, vtg);
  mem_gemm<<<dim3(8, 8, B_), 256, 0, stream>>>(vtg, ktg, mem);
}